// Round 1
// baseline (2137.029 us; speedup 1.0000x reference)
//
#include <hip/hip_runtime.h>
#include <hip/hip_bf16.h>

#define Vv 32000
#define Bz 32
#define Tz 256
#define Hz 256

typedef __attribute__((ext_vector_type(8))) short short8;
typedef __attribute__((ext_vector_type(4))) float f32x4;

__device__ __forceinline__ float sigm(float x) { return 1.f / (1.f + __expf(-x)); }

// ---------- transpose+convert softmax_w [256][32000] f32 -> SWT [32000][256] bf16
__global__ __launch_bounds__(256) void k_swt(const float* __restrict__ sw,
                                             __hip_bfloat16* __restrict__ swt) {
    __shared__ float tile[64][65];
    int kt = blockIdx.x & 3, vt = blockIdx.x >> 2;
    int k0 = kt * 64, v0 = vt * 64, tid = threadIdx.x;
#pragma unroll
    for (int p = 0; p < 16; ++p) {
        int lin = p * 256 + tid;
        int kk = lin >> 6, vvi = lin & 63;
        tile[kk][vvi] = sw[(size_t)(k0 + kk) * Vv + v0 + vvi];
    }
    __syncthreads();
#pragma unroll
    for (int p = 0; p < 16; ++p) {
        int lin = p * 256 + tid;
        int vvi = lin >> 6, kk = lin & 63;
        swt[(size_t)(v0 + vvi) * 256 + k0 + kk] = __float2bfloat16(tile[kk][vvi]);
    }
}

// ---------- one pipeline node: layer1(t=node) on blocks 0..127, layer2(t=node-1) on 128..255
// Each block: 2 batches x 128 z-columns (one 32-wide n-chunk across all 4 gates).
__global__ __launch_bounds__(512) void k_step(int node,
    const int* __restrict__ inp, const float* __restrict__ emb,
    const float* __restrict__ W1, const float* __restrict__ b1v,
    const float* __restrict__ W2, const float* __restrict__ b2v,
    float* __restrict__ c1, float* __restrict__ c2,
    float* __restrict__ h1buf, float* __restrict__ h2buf,
    float* __restrict__ houtF, __hip_bfloat16* __restrict__ houtB)
{
    int bid = blockIdx.x;
    int which = bid >> 7;          // 0 = layer1, 1 = layer2
    int bp = bid & 127;
    int bpair = bp >> 3, cch = bp & 7;
    int b0 = bpair * 2;
    int tid = threadIdx.x;

    int t = which ? (node - 1) : node;
    if (which ? (t < 0) : (t >= Tz)) return;

    __shared__ float in_[1024];        // layout [k][bb]
    __shared__ float zp[4][2][128];
    __shared__ float zf[2][128];

    const float* W  = which ? W2 : W1;
    const float* bv = which ? b2v : b1v;
    float* cst      = which ? c2 : c1;

    int pin = t & 1, pout = (t + 1) & 1;
    const float *src0, *src1, *hprev0, *hprev1;
    float *hout0, *hout1;
    if (!which) {
        src0 = emb + (size_t)inp[(b0    ) * Tz + t] * Hz;
        src1 = emb + (size_t)inp[(b0 + 1) * Tz + t] * Hz;
        hprev0 = h1buf + pin * 8192 + (b0    ) * Hz;
        hprev1 = h1buf + pin * 8192 + (b0 + 1) * Hz;
        hout0 = h1buf + pout * 8192 + (b0    ) * Hz;
        hout1 = h1buf + pout * 8192 + (b0 + 1) * Hz;
    } else {
        src0 = h1buf + pout * 8192 + (b0    ) * Hz;   // h1 of this step (written last node)
        src1 = h1buf + pout * 8192 + (b0 + 1) * Hz;
        hprev0 = h2buf + pin * 8192 + (b0    ) * Hz;
        hprev1 = h2buf + pin * 8192 + (b0 + 1) * Hz;
        hout0 = h2buf + pout * 8192 + (b0    ) * Hz;
        hout1 = h2buf + pout * 8192 + (b0 + 1) * Hz;
    }

    // stage concat inputs [x ; h_prev] for both batches, interleaved [k*2+bb]
#pragma unroll
    for (int q = 0; q < 2; ++q) {
        int e = q * 512 + tid;
        int kk = e >> 1, bb = e & 1;
        float val;
        if (kk < Hz) val = (bb ? src1 : src0)[kk];
        else         val = (bb ? hprev1 : hprev0)[kk - Hz];
        in_[e] = val;
    }
    __syncthreads();

    int s4 = tid >> 7;             // k-quarter 0..3
    int lc = tid & 127;
    int g = lc >> 5, nl = lc & 31;
    int zcol = g * 256 + cch * 32 + nl;
    const float* Wp = W + (size_t)(s4 * 128) * 1024 + zcol;
    const float* ip = in_ + s4 * 256;
    float a0 = 0.f, a1 = 0.f;
#pragma unroll 8
    for (int k = 0; k < 128; k += 2) {
        float4 iv = *(const float4*)&ip[k * 2];
        float wv0 = Wp[(size_t)k * 1024];
        float wv1 = Wp[(size_t)(k + 1) * 1024];
        a0 += iv.x * wv0; a1 += iv.y * wv0;
        a0 += iv.z * wv1; a1 += iv.w * wv1;
    }
    zp[s4][0][lc] = a0;
    zp[s4][1][lc] = a1;
    __syncthreads();

    if (tid < 256) {
        int bb = tid >> 7, l2c = tid & 127;
        int zc = (l2c >> 5) * 256 + cch * 32 + (l2c & 31);
        zf[bb][l2c] = zp[0][bb][l2c] + zp[1][bb][l2c] + zp[2][bb][l2c] + zp[3][bb][l2c] + bv[zc];
    }
    __syncthreads();

    if (tid < 64) {
        int bb = tid >> 5, ln = tid & 31;
        int n = cch * 32 + ln;
        int b = b0 + bb;
        float iz = zf[bb][ln], jz = zf[bb][32 + ln], fz = zf[bb][64 + ln], oz = zf[bb][96 + ln];
        float cv = cst[b * Hz + n];
        float cn = cv * sigm(fz + 1.f) + sigm(iz) * tanhf(jz);
        cst[b * Hz + n] = cn;
        float hv = tanhf(cn) * sigm(oz);
        (bb ? hout1 : hout0)[n] = hv;
        if (which) {
            size_t row = (size_t)b * Tz + t;   // batch-major flatten, matches reference
            houtF[row * Hz + n] = hv;
            houtB[row * Hz + n] = __float2bfloat16(hv);
        }
    }
}

// ---------- logits GEMM (bf16 MFMA) + streaming sum-of-exp per row
#define STR 136   // LDS row stride in bf16 elems: 16B-aligned, conflict-free for b128 frags
__global__ __launch_bounds__(256) void k_gemm(const __hip_bfloat16* __restrict__ Abf,
    const __hip_bfloat16* __restrict__ Bbf, const float* __restrict__ sb,
    float* __restrict__ row_sum)
{
    __shared__ unsigned short As[64 * STR];
    __shared__ unsigned short Bs[64 * STR];
    int tid = threadIdx.x;
    int c0 = blockIdx.x * 64;
    size_t r0 = (size_t)blockIdx.y * 64;
    int l = tid & 63, w = tid >> 6, lr = l & 15, lk = l >> 4;

    f32x4 acc[4];
#pragma unroll
    for (int f = 0; f < 4; ++f) acc[f] = (f32x4){0.f, 0.f, 0.f, 0.f};

    for (int kh = 0; kh < 2; ++kh) {
#pragma unroll
        for (int p = 0; p < 4; ++p) {
            int u = p * 256 + tid;
            int v = u >> 4, kq = u & 15;
            *(uint4*)&As[v * STR + kq * 8] =
                *(const uint4*)&Abf[(r0 + v) * 256 + kh * 128 + kq * 8];
            *(uint4*)&Bs[v * STR + kq * 8] =
                *(const uint4*)&Bbf[((size_t)c0 + v) * 256 + kh * 128 + kq * 8];
        }
        __syncthreads();
#pragma unroll
        for (int ks = 0; ks < 4; ++ks) {
            short8 a = *(const short8*)&As[(w * 16 + lr) * STR + ks * 32 + lk * 8];
#pragma unroll
            for (int f = 0; f < 4; ++f) {
                short8 bfr = *(const short8*)&Bs[(f * 16 + lr) * STR + ks * 32 + lk * 8];
                acc[f] = __builtin_amdgcn_mfma_f32_16x16x32_bf16(a, bfr, acc[f], 0, 0, 0);
            }
        }
        __syncthreads();
    }

    // epilogue: sum_j over this 64-col stripe of exp(logit + sb), reduce across cols, atomic per row
    float sums[4] = {0.f, 0.f, 0.f, 0.f};
#pragma unroll
    for (int f = 0; f < 4; ++f) {
        float sbv = sb[c0 + f * 16 + lr];
#pragma unroll
        for (int j = 0; j < 4; ++j) sums[j] += __expf(acc[f][j] + sbv);
    }
#pragma unroll
    for (int m = 1; m <= 8; m <<= 1) {
#pragma unroll
        for (int j = 0; j < 4; ++j) sums[j] += __shfl_xor(sums[j], m);
    }
    if (lr == 0) {
#pragma unroll
        for (int j = 0; j < 4; ++j)
            atomicAdd(&row_sum[r0 + w * 16 + lk * 4 + j], sums[j]);
    }
}

// ---------- per-row loss: log(sum_exp) - (exact fp32 target logit), reduce to scalar
__global__ __launch_bounds__(256) void k_loss(const float* __restrict__ houtF,
    const float* __restrict__ sw, const float* __restrict__ sb,
    const int* __restrict__ tgts, const float* __restrict__ row_sum,
    float* __restrict__ out)
{
    int r = blockIdx.x * 256 + threadIdx.x;
    int tg = tgts[r];
    const float* h = houtF + (size_t)r * Hz;
    const float* wp = sw + tg;
    float acc = 0.f;
#pragma unroll 8
    for (int k = 0; k < Hz; ++k) acc += h[k] * wp[(size_t)k * Vv];
    float loss = logf(row_sum[r]) - (acc + sb[tg]);
#pragma unroll
    for (int m = 1; m < 64; m <<= 1) loss += __shfl_xor(loss, m);
    __shared__ float red[4];
    int l = threadIdx.x & 63, wv = threadIdx.x >> 6;
    if (l == 0) red[wv] = loss;
    __syncthreads();
    if (threadIdx.x == 0) {
        float s = red[0] + red[1] + red[2] + red[3];
        atomicAdd(out, s * (1.f / 8192.f));
    }
}

extern "C" void kernel_launch(void* const* d_in, const int* in_sizes, int n_in,
                              void* d_out, int out_size, void* d_ws, size_t ws_size,
                              hipStream_t stream)
{
    const int*   inp = (const int*)d_in[0];
    const int*   tgt = (const int*)d_in[1];
    const float* emb = (const float*)d_in[2];
    const float* W1  = (const float*)d_in[3];
    const float* b1  = (const float*)d_in[4];
    const float* W2  = (const float*)d_in[5];
    const float* b2  = (const float*)d_in[6];
    const float* sw  = (const float*)d_in[7];
    const float* sb  = (const float*)d_in[8];
    float* out = (float*)d_out;

    char* ws = (char*)d_ws;
    size_t off = 0;
    __hip_bfloat16* SWT = (__hip_bfloat16*)(ws + off); off += (size_t)Vv * Hz * 2;      // 16,384,000
    float* HoutF = (float*)(ws + off);                 off += (size_t)8192 * Hz * 4;    //  8,388,608
    __hip_bfloat16* HoutB = (__hip_bfloat16*)(ws + off); off += (size_t)8192 * Hz * 2;  //  4,194,304
    float* row_sum = (float*)(ws + off);               off += 8192 * 4;
    float* c1 = (float*)(ws + off);                    off += 32 * 256 * 4;
    float* c2 = (float*)(ws + off);                    off += 32 * 256 * 4;
    float* h1buf = (float*)(ws + off);                 off += 2 * 32 * 256 * 4;
    float* h2buf = (float*)(ws + off);                 off += 2 * 32 * 256 * 4;
    // total ~27.9 MiB

    hipMemsetAsync(row_sum, 0, 8192 * 4, stream);
    hipMemsetAsync(c1, 0, (32 * 256 * 4) * 2 + (2 * 32 * 256 * 4) * 2, stream); // c1,c2,h1,h2
    hipMemsetAsync(out, 0, sizeof(float), stream);

    k_swt<<<2000, 256, 0, stream>>>(sw, SWT);

    for (int node = 0; node <= 256; ++node)
        k_step<<<256, 512, 0, stream>>>(node, inp, emb, W1, b1, W2, b2,
                                        c1, c2, h1buf, h2buf, HoutF, HoutB);

    k_gemm<<<dim3(500, 128), 256, 0, stream>>>(HoutB, SWT, sb, row_sum);
    k_loss<<<32, 256, 0, stream>>>(HoutF, sw, sb, tgt, row_sum, out);
}

// Round 2
// 1949.581 us; speedup vs baseline: 1.0961x; 1.0961x over previous
//
#include <hip/hip_runtime.h>
#include <hip/hip_bf16.h>

#define Vv 32000
#define Tz 256
#define Hz 256

typedef __attribute__((ext_vector_type(8))) short short8;
typedef __attribute__((ext_vector_type(4))) float f32x4;

__device__ __forceinline__ float sigm(float x) { return 1.f / (1.f + __expf(-x)); }
__device__ __forceinline__ unsigned short f2bf(float x) {
    union { __hip_bfloat16 h; unsigned short u; } cv; cv.h = __float2bfloat16(x); return cv.u;
}

// ---------- transpose+convert softmax_w [256][32000] f32 -> SWT [32000][256] bf16
__global__ __launch_bounds__(256) void k_swt(const float* __restrict__ sw,
                                             __hip_bfloat16* __restrict__ swt) {
    __shared__ float tile[64][65];
    int kt = blockIdx.x & 3, vt = blockIdx.x >> 2;
    int k0 = kt * 64, v0 = vt * 64, tid = threadIdx.x;
#pragma unroll
    for (int p = 0; p < 16; ++p) {
        int lin = p * 256 + tid;
        int kk = lin >> 6, vvi = lin & 63;
        tile[kk][vvi] = sw[(size_t)(k0 + kk) * Vv + v0 + vvi];
    }
    __syncthreads();
#pragma unroll
    for (int p = 0; p < 16; ++p) {
        int lin = p * 256 + tid;
        int vvi = lin >> 6, kk = lin & 63;
        swt[(size_t)(v0 + vvi) * 256 + k0 + kk] = __float2bfloat16(tile[kk][vvi]);
    }
}

// ---------- embedding gather -> xs_bf [T][B][256] bf16
__global__ __launch_bounds__(64) void k_embed(const int* __restrict__ inp,
    const float* __restrict__ emb, __hip_bfloat16* __restrict__ xs) {
    int row = blockIdx.x;              // t*32 + b
    int t = row >> 5, b = row & 31;
    const float* src = emb + (size_t)inp[b * Tz + t] * Hz;
    int tid = threadIdx.x;
    float4 v = *(const float4*)&src[tid * 4];
    __hip_bfloat16* dst = xs + (size_t)row * Hz + tid * 4;
    dst[0] = __float2bfloat16(v.x); dst[1] = __float2bfloat16(v.y);
    dst[2] = __float2bfloat16(v.z); dst[3] = __float2bfloat16(v.w);
}

// ---------- persistent 2-layer LSTM, 64 blocks (32 per layer), self grid-barrier
__device__ __forceinline__ void grid_barrier(unsigned* cnt) {
    __syncthreads();
    if (threadIdx.x == 0) {
        unsigned ticket = __hip_atomic_fetch_add(cnt, 1u, __ATOMIC_RELEASE, __HIP_MEMORY_SCOPE_AGENT);
        unsigned target = (ticket / 64u + 1u) * 64u;
        while (__hip_atomic_load(cnt, __ATOMIC_ACQUIRE, __HIP_MEMORY_SCOPE_AGENT) < target)
            __builtin_amdgcn_s_sleep(8);
    }
    __syncthreads();
}

__global__ __launch_bounds__(256) void k_lstm(
    const __hip_bfloat16* __restrict__ xs,     // [256][32][256]
    const float* __restrict__ W1, const float* __restrict__ b1v,
    const float* __restrict__ W2, const float* __restrict__ b2v,
    __hip_bfloat16* __restrict__ h1buf,        // [2][32][256]
    __hip_bfloat16* __restrict__ h2buf,
    float* __restrict__ houtF, __hip_bfloat16* __restrict__ houtB,
    unsigned* __restrict__ cnt)
{
    __shared__ __align__(16) unsigned short Wl[32 * 528];   // [zc-row r=g*8+jj][k 512], bf16
    __shared__ __align__(16) unsigned short inh[32 * 272];  // [b][k-half 256]; aliased as zbuf f32[16*64*4]
    __shared__ float zl[32 * 33];
    __shared__ float c_l[256];                               // [b][jj] : 32*8

    int bid = blockIdx.x;
    int which = bid >> 5;          // 0=layer1, 1=layer2
    int bp = bid & 31;
    int nb = bp * 8;               // 8 n-cols per gate
    int tid = threadIdx.x;
    int w = tid >> 6, l = tid & 63, lr = l & 15, lk = l >> 4;

    const float* W    = which ? W2 : W1;
    const float* bptr = which ? b2v : b1v;

    // stage W slice (once): Wl[r][k] = bf16(W[k][zc(r)]), r = g*8+jj
    {
        int u = tid & 31, klane = tid >> 5;
        int zc = ((u >> 3) << 8) + nb + (u & 7);
#pragma unroll 8
        for (int it = 0; it < 64; ++it) {
            int k = klane + it * 8;
            Wl[u * 528 + k] = f2bf(W[(size_t)k * 1024 + zc]);
        }
    }
    c_l[tid] = 0.f;
    // bias for reduce phase: this thread's frag column r = (w&1)*16 + lr
    float bfrag;
    {
        int r = ((w & 1) << 4) + lr;
        bfrag = bptr[((r >> 3) << 8) + nb + (r & 7)];
    }
    __syncthreads();

    float* zbuf = (float*)inh;

    for (int node = 0; node <= 256; ++node) {
        int t = which ? (node - 1) : node;
        bool valid = which ? (t >= 0) : (t < 256);
        if (valid) {
            f32x4 acc[2][2];
#pragma unroll
            for (int m = 0; m < 2; ++m)
#pragma unroll
                for (int n = 0; n < 2; ++n) acc[m][n] = (f32x4){0.f, 0.f, 0.f, 0.f};

            const unsigned short* h1p = (const unsigned short*)h1buf + ((node - 1) & 1) * 8192;
#pragma unroll
            for (int kh = 0; kh < 2; ++kh) {
                const unsigned short* src;
                if (!which) src = kh ? h1p : (const unsigned short*)xs + (size_t)t * 8192;
                else        src = kh ? (const unsigned short*)h2buf + (node & 1) * 8192 : h1p;
                // stage 32x256 bf16 half into inh
#pragma unroll
                for (int i = 0; i < 4; ++i) {
                    int fi = i * 256 + tid;
                    int b = fi >> 5, seg = fi & 31;
                    *(short8*)&inh[b * 272 + seg * 8] = *(const short8*)&src[fi * 8];
                }
                __syncthreads();
#pragma unroll
                for (int s = 0; s < 2; ++s) {
                    int kl = w * 64 + s * 32;
                    short8 a0 = *(const short8*)&inh[lr * 272 + kl + lk * 8];
                    short8 a1 = *(const short8*)&inh[(16 + lr) * 272 + kl + lk * 8];
                    short8 q0 = *(const short8*)&Wl[lr * 528 + kh * 256 + kl + lk * 8];
                    short8 q1 = *(const short8*)&Wl[(16 + lr) * 528 + kh * 256 + kl + lk * 8];
                    acc[0][0] = __builtin_amdgcn_mfma_f32_16x16x32_bf16(a0, q0, acc[0][0], 0, 0, 0);
                    acc[0][1] = __builtin_amdgcn_mfma_f32_16x16x32_bf16(a0, q1, acc[0][1], 0, 0, 0);
                    acc[1][0] = __builtin_amdgcn_mfma_f32_16x16x32_bf16(a1, q0, acc[1][0], 0, 0, 0);
                    acc[1][1] = __builtin_amdgcn_mfma_f32_16x16x32_bf16(a1, q1, acc[1][1], 0, 0, 0);
                }
                __syncthreads();
            }
            // write partial frags to zbuf (aliases inh — safe after the sync above)
#pragma unroll
            for (int m = 0; m < 2; ++m)
#pragma unroll
                for (int n = 0; n < 2; ++n)
                    *(f32x4*)&zbuf[((w * 4 + m * 2 + n) * 64 + l) * 4] = acc[m][n];
            __syncthreads();
            // reduce across waves: wave w owns frag (m=w>>1, n=w&1); add bias; write zl[b][r]
            {
                int m = w >> 1, n = w & 1;
                f32x4 z = (f32x4){0.f, 0.f, 0.f, 0.f};
#pragma unroll
                for (int wv = 0; wv < 4; ++wv)
                    z += *(const f32x4*)&zbuf[((wv * 4 + m * 2 + n) * 64 + l) * 4];
                int r = n * 16 + lr;
#pragma unroll
                for (int j = 0; j < 4; ++j) {
                    int b = m * 16 + lk * 4 + j;
                    zl[b * 33 + r] = z[j] + bfrag;
                }
            }
            __syncthreads();
            // epilogue: thread = (b, jj)
            {
                int jj = tid & 7, b = tid >> 3;
                float zi = zl[b * 33 + jj];
                float zj = zl[b * 33 + 8 + jj];
                float zf = zl[b * 33 + 16 + jj];
                float zo = zl[b * 33 + 24 + jj];
                float c = c_l[tid];
                float cn = c * sigm(zf + 1.f) + sigm(zi) * tanhf(zj);
                c_l[tid] = cn;
                float hv = tanhf(cn) * sigm(zo);
                int col = nb + jj;
                if (!which) {
                    ((unsigned short*)h1buf)[(node & 1) * 8192 + b * 256 + col] = f2bf(hv);
                } else {
                    ((unsigned short*)h2buf)[((node - 1) & 1) * 8192 + b * 256 + col] = f2bf(hv);
                    size_t row = (size_t)b * Tz + t;
                    houtF[row * 256 + col] = hv;
                    ((unsigned short*)houtB)[row * 256 + col] = f2bf(hv);
                }
            }
        }
        grid_barrier(cnt);
    }
}

// ---------- logits GEMM: 128x128 tile, BK=64, XOR-swizzled LDS, streaming sum-of-exp
__global__ __launch_bounds__(256) void k_gemm(const __hip_bfloat16* __restrict__ Abf,
    const __hip_bfloat16* __restrict__ Bbf, const float* __restrict__ sb,
    float* __restrict__ row_sum)
{
    __shared__ __align__(16) unsigned short As[128 * 64];
    __shared__ __align__(16) unsigned short Bs[128 * 64];
    int tid = threadIdx.x;
    size_t r0 = (size_t)blockIdx.x * 128;   // rows fast-varying: consecutive blocks share B stripe
    size_t c0 = (size_t)blockIdx.y * 128;
    int l = tid & 63, w = tid >> 6, lr = l & 15, lk = l >> 4;

    f32x4 acc[2][8];
#pragma unroll
    for (int m = 0; m < 2; ++m)
#pragma unroll
        for (int f = 0; f < 8; ++f) acc[m][f] = (f32x4){0.f, 0.f, 0.f, 0.f};

    const unsigned short* A = (const unsigned short*)Abf;
    const unsigned short* B = (const unsigned short*)Bbf;

    for (int kt = 0; kt < 4; ++kt) {
#pragma unroll
        for (int i = 0; i < 4; ++i) {
            int fi = i * 256 + tid;
            int row = fi >> 3, seg = fi & 7;
            int dseg = seg ^ (row & 7);       // store-permute; read applies same XOR -> identity
            *(short8*)&As[row * 64 + dseg * 8] =
                *(const short8*)&A[(r0 + row) * 256 + kt * 64 + seg * 8];
            *(short8*)&Bs[row * 64 + dseg * 8] =
                *(const short8*)&B[(c0 + row) * 256 + kt * 64 + seg * 8];
        }
        __syncthreads();
#pragma unroll
        for (int ks = 0; ks < 2; ++ks) {
            short8 a[2];
#pragma unroll
            for (int m = 0; m < 2; ++m) {
                int row = w * 32 + m * 16 + lr;
                a[m] = *(const short8*)&As[row * 64 + ((ks * 4 + lk) ^ (row & 7)) * 8];
            }
#pragma unroll
            for (int f = 0; f < 8; ++f) {
                int row = f * 16 + lr;
                short8 bfr = *(const short8*)&Bs[row * 64 + ((ks * 4 + lk) ^ (row & 7)) * 8];
#pragma unroll
                for (int m = 0; m < 2; ++m)
                    acc[m][f] = __builtin_amdgcn_mfma_f32_16x16x32_bf16(a[m], bfr, acc[m][f], 0, 0, 0);
            }
        }
        __syncthreads();
    }

    float sums[2][4] = {{0.f,0.f,0.f,0.f},{0.f,0.f,0.f,0.f}};
#pragma unroll
    for (int f = 0; f < 8; ++f) {
        float sbv = sb[c0 + f * 16 + lr];
#pragma unroll
        for (int m = 0; m < 2; ++m)
#pragma unroll
            for (int j = 0; j < 4; ++j) sums[m][j] += __expf(acc[m][f][j] + sbv);
    }
#pragma unroll
    for (int msk = 1; msk <= 8; msk <<= 1)
#pragma unroll
        for (int m = 0; m < 2; ++m)
#pragma unroll
            for (int j = 0; j < 4; ++j) sums[m][j] += __shfl_xor(sums[m][j], msk);
    if (lr == 0) {
#pragma unroll
        for (int m = 0; m < 2; ++m)
#pragma unroll
            for (int j = 0; j < 4; ++j)
                atomicAdd(&row_sum[r0 + w * 32 + m * 16 + lk * 4 + j], sums[m][j]);
    }
}

// ---------- per-row loss: log(sum_exp) - exact fp32 target logit, reduce to scalar
__global__ __launch_bounds__(256) void k_loss(const float* __restrict__ houtF,
    const float* __restrict__ sw, const float* __restrict__ sb,
    const int* __restrict__ tgts, const float* __restrict__ row_sum,
    float* __restrict__ out)
{
    int r = blockIdx.x * 256 + threadIdx.x;
    int tg = tgts[r];
    const float* h = houtF + (size_t)r * Hz;
    const float* wp = sw + tg;
    float acc = 0.f;
#pragma unroll 8
    for (int k = 0; k < Hz; ++k) acc += h[k] * wp[(size_t)k * Vv];
    float loss = logf(row_sum[r]) - (acc + sb[tg]);
#pragma unroll
    for (int m = 1; m < 64; m <<= 1) loss += __shfl_xor(loss, m);
    __shared__ float red[4];
    int l = threadIdx.x & 63, wv = threadIdx.x >> 6;
    if (l == 0) red[wv] = loss;
    __syncthreads();
    if (threadIdx.x == 0) {
        float s = red[0] + red[1] + red[2] + red[3];
        atomicAdd(out, s * (1.f / 8192.f));
    }
}

extern "C" void kernel_launch(void* const* d_in, const int* in_sizes, int n_in,
                              void* d_out, int out_size, void* d_ws, size_t ws_size,
                              hipStream_t stream)
{
    const int*   inp = (const int*)d_in[0];
    const int*   tgt = (const int*)d_in[1];
    const float* emb = (const float*)d_in[2];
    const float* W1  = (const float*)d_in[3];
    const float* b1  = (const float*)d_in[4];
    const float* W2  = (const float*)d_in[5];
    const float* b2  = (const float*)d_in[6];
    const float* sw  = (const float*)d_in[7];
    const float* sb  = (const float*)d_in[8];
    float* out = (float*)d_out;

    char* ws = (char*)d_ws;
    size_t off = 0;
    __hip_bfloat16* SWT  = (__hip_bfloat16*)(ws + off); off += (size_t)Vv * Hz * 2;       // 16,384,000
    __hip_bfloat16* XS   = (__hip_bfloat16*)(ws + off); off += (size_t)Tz * 32 * Hz * 2;  //  4,194,304
    float* HoutF         = (float*)(ws + off);          off += (size_t)8192 * Hz * 4;     //  8,388,608
    __hip_bfloat16* HoutB= (__hip_bfloat16*)(ws + off); off += (size_t)8192 * Hz * 2;     //  4,194,304
    float* row_sum       = (float*)(ws + off);          off += 8192 * 4;                  //     32,768
    __hip_bfloat16* h1b  = (__hip_bfloat16*)(ws + off); off += 2 * 32 * Hz * 2;           //     32,768
    __hip_bfloat16* h2b  = (__hip_bfloat16*)(ws + off); off += 2 * 32 * Hz * 2;           //     32,768
    unsigned* cnt        = (unsigned*)(ws + off);       off += 16;
    // total ~33.3 MiB

    // zero row_sum + h1b + h2b + cnt (contiguous) and out
    hipMemsetAsync(row_sum, 0, 8192 * 4 + 2 * 32768 + 16, stream);
    hipMemsetAsync(out, 0, sizeof(float), stream);

    k_swt<<<2000, 256, 0, stream>>>(sw, SWT);
    k_embed<<<8192, 64, 0, stream>>>(inp, emb, XS);
    k_lstm<<<64, 256, 0, stream>>>(XS, W1, b1, W2, b2, h1b, h2b, HoutF, HoutB, cnt);
    k_gemm<<<dim3(64, 250), 256, 0, stream>>>(HoutB, SWT, sb, row_sum);
    k_loss<<<32, 256, 0, stream>>>(HoutF, sw, sb, tgt, row_sum, out);
}

// Round 3
// 1560.873 us; speedup vs baseline: 1.3691x; 1.2490x over previous
//
#include <hip/hip_runtime.h>
#include <hip/hip_bf16.h>

#define Vv 32000
#define Tz 256
#define Hz 256

typedef __attribute__((ext_vector_type(8))) short short8;
typedef __attribute__((ext_vector_type(4))) float f32x4;

__device__ __forceinline__ float sigm(float x) { return 1.f / (1.f + __expf(-x)); }
__device__ __forceinline__ unsigned short f2bf(float x) {
    union { __hip_bfloat16 h; unsigned short u; } cv; cv.h = __float2bfloat16(x); return cv.u;
}

// ---------- transpose+convert softmax_w [256][32000] f32 -> SWT [32000][256] bf16
__global__ __launch_bounds__(256) void k_swt(const float* __restrict__ sw,
                                             __hip_bfloat16* __restrict__ swt) {
    __shared__ float tile[64][65];
    int kt = blockIdx.x & 3, vt = blockIdx.x >> 2;
    int k0 = kt * 64, v0 = vt * 64, tid = threadIdx.x;
#pragma unroll
    for (int p = 0; p < 16; ++p) {
        int lin = p * 256 + tid;
        int kk = lin >> 6, vvi = lin & 63;
        tile[kk][vvi] = sw[(size_t)(k0 + kk) * Vv + v0 + vvi];
    }
    __syncthreads();
#pragma unroll
    for (int p = 0; p < 16; ++p) {
        int lin = p * 256 + tid;
        int vvi = lin >> 6, kk = lin & 63;
        swt[(size_t)(v0 + vvi) * 256 + k0 + kk] = __float2bfloat16(tile[kk][vvi]);
    }
}

// ---------- embedding gather -> xs_bf [T][B][256] bf16
__global__ __launch_bounds__(64) void k_embed(const int* __restrict__ inp,
    const float* __restrict__ emb, __hip_bfloat16* __restrict__ xs) {
    int row = blockIdx.x;              // t*32 + b
    int t = row >> 5, b = row & 31;
    const float* src = emb + (size_t)inp[b * Tz + t] * Hz;
    int tid = threadIdx.x;
    float4 v = *(const float4*)&src[tid * 4];
    __hip_bfloat16* dst = xs + (size_t)row * Hz + tid * 4;
    dst[0] = __float2bfloat16(v.x); dst[1] = __float2bfloat16(v.y);
    dst[2] = __float2bfloat16(v.z); dst[3] = __float2bfloat16(v.w);
}

// ---------- contention-free grid barrier: per-block flag store + 64-lane poll
// flags: unsigned[64 * 16] (each flag on its own 64B line), zeroed before launch.
__device__ __forceinline__ void gbar(unsigned* flags, unsigned target, int bid) {
    __syncthreads();   // HIP syncthreads drains vmcnt per wave before s_barrier
    if (threadIdx.x < 64) {
        if (threadIdx.x == 0)
            __hip_atomic_store(&flags[bid * 16], target, __ATOMIC_RELEASE,
                               __HIP_MEMORY_SCOPE_AGENT);
        unsigned v;
        do {
            v = __hip_atomic_load(&flags[threadIdx.x * 16], __ATOMIC_ACQUIRE,
                                  __HIP_MEMORY_SCOPE_AGENT);
        } while (!__all((int)(v >= target)));
    }
    __syncthreads();
}

// ---------- persistent 2-layer LSTM, 64 blocks (32 per layer)
#define WSTR 520   // LDS row stride (bf16 elems): 1040B -> 16B-slot advance 65 (odd) -> conflict-free
__global__ __launch_bounds__(256) void k_lstm(
    const __hip_bfloat16* __restrict__ xs,     // [256][32][256]
    const float* __restrict__ W1, const float* __restrict__ b1v,
    const float* __restrict__ W2, const float* __restrict__ b2v,
    __hip_bfloat16* __restrict__ h1buf,        // [2][32][256]
    __hip_bfloat16* __restrict__ h2buf,
    float* __restrict__ houtF, __hip_bfloat16* __restrict__ houtB,
    unsigned* __restrict__ flags)
{
    __shared__ __align__(16) unsigned short Wl[32 * WSTR];   // W slice [zcol r 0..31][k 0..511]
    __shared__ __align__(16) unsigned short inh[32 * WSTR];  // [batch 0..31][k 0..511]
    __shared__ float zl[32 * 33];
    __shared__ float c_l[256];                               // c state [b][jj]

    int bid = blockIdx.x;
    int which = bid >> 5;          // 0=layer1, 1=layer2
    int bp = bid & 31;
    int nb = bp * 8;               // 8 n-cols per gate
    int tid = threadIdx.x;
    int w = tid >> 6, l = tid & 63, lr = l & 15, lk = l >> 4;

    const float* W    = which ? W2 : W1;
    const float* bptr = which ? b2v : b1v;

    // stage W slice once: Wl[r][k] = bf16(W[k][zc(r)]), r = g*8+jj
    {
        int u = tid & 31, klane = tid >> 5;
        int zc = ((u >> 3) << 8) + nb + (u & 7);
#pragma unroll 8
        for (int it = 0; it < 64; ++it) {
            int k = klane + it * 8;
            Wl[u * WSTR + k] = f2bf(W[(size_t)k * 1024 + zc]);
        }
    }
    c_l[tid] = 0.f;
    // bias for this thread's frag column r = (w&1)*16 + lr
    float bfrag;
    {
        int r = ((w & 1) << 4) + lr;
        bfrag = bptr[((r >> 3) << 8) + nb + (r & 7)];
    }
    __syncthreads();

    int arow = ((w >> 1) << 4) + lr;   // batch row of this wave's tile
    int brow = ((w & 1) << 4) + lr;    // zcol row of this wave's tile

    for (int node = 0; node <= 256; ++node) {
        int t = which ? (node - 1) : node;
        bool valid = which ? (t >= 0) : (t < 256);
        if (valid) {
            // ---- stage [x;h] (32 x 512 bf16) in one pass
            const unsigned short* h1p = (const unsigned short*)h1buf + ((node - 1) & 1) * 8192;
            const unsigned short *s0, *s1;
            if (!which) { s0 = (const unsigned short*)xs + (size_t)t * 8192; s1 = h1p; }
            else        { s0 = h1p; s1 = (const unsigned short*)h2buf + (node & 1) * 8192; }
#pragma unroll
            for (int i = 0; i < 8; ++i) {
                int e = (i * 256 + tid) * 8;
                int b = e >> 9, k = e & 511;
                const unsigned short* sp = (k < 256) ? &s0[b * 256 + k] : &s1[b * 256 + k - 256];
                *(short8*)&inh[b * WSTR + k] = *(const short8*)sp;
            }
            __syncthreads();

            // ---- full-K MFMA: each wave owns one 16x16 tile (batch x zcol)
            f32x4 acc0 = (f32x4){0.f, 0.f, 0.f, 0.f};
            f32x4 acc1 = (f32x4){0.f, 0.f, 0.f, 0.f};
#pragma unroll
            for (int ks = 0; ks < 16; ks += 2) {
                short8 a0 = *(const short8*)&inh[arow * WSTR + ks * 32 + lk * 8];
                short8 q0 = *(const short8*)&Wl[brow * WSTR + ks * 32 + lk * 8];
                short8 a1 = *(const short8*)&inh[arow * WSTR + (ks + 1) * 32 + lk * 8];
                short8 q1 = *(const short8*)&Wl[brow * WSTR + (ks + 1) * 32 + lk * 8];
                acc0 = __builtin_amdgcn_mfma_f32_16x16x32_bf16(a0, q0, acc0, 0, 0, 0);
                acc1 = __builtin_amdgcn_mfma_f32_16x16x32_bf16(a1, q1, acc1, 0, 0, 0);
            }
            f32x4 z = acc0 + acc1;

            // ---- z -> LDS (bias added), then epilogue
            {
                int m = w >> 1, n = w & 1;
#pragma unroll
                for (int j = 0; j < 4; ++j)
                    zl[(m * 16 + lk * 4 + j) * 33 + n * 16 + lr] = z[j] + bfrag;
            }
            __syncthreads();
            {
                int jj = tid & 7, b = tid >> 3;
                float zi = zl[b * 33 + jj];
                float zj = zl[b * 33 + 8 + jj];
                float zf = zl[b * 33 + 16 + jj];
                float zo = zl[b * 33 + 24 + jj];
                float c = c_l[tid];
                float cn = c * sigm(zf + 1.f) + sigm(zi) * tanhf(zj);
                c_l[tid] = cn;
                float hv = tanhf(cn) * sigm(zo);
                int col = nb + jj;
                if (!which) {
                    ((unsigned short*)h1buf)[(node & 1) * 8192 + b * 256 + col] = f2bf(hv);
                } else {
                    ((unsigned short*)h2buf)[((node - 1) & 1) * 8192 + b * 256 + col] = f2bf(hv);
                    size_t row = (size_t)b * Tz + t;
                    houtF[row * 256 + col] = hv;
                    ((unsigned short*)houtB)[row * 256 + col] = f2bf(hv);
                }
            }
        }
        gbar(flags, (unsigned)(node + 1), bid);
    }
}

// ---------- logits GEMM: 128x128 tile, BK=64, XOR-swizzled LDS, streaming sum-of-exp
__global__ __launch_bounds__(256) void k_gemm(const __hip_bfloat16* __restrict__ Abf,
    const __hip_bfloat16* __restrict__ Bbf, const float* __restrict__ sb,
    float* __restrict__ row_sum)
{
    __shared__ __align__(16) unsigned short As[128 * 64];
    __shared__ __align__(16) unsigned short Bs[128 * 64];
    int tid = threadIdx.x;
    size_t r0 = (size_t)blockIdx.x * 128;
    size_t c0 = (size_t)blockIdx.y * 128;
    int l = tid & 63, w = tid >> 6, lr = l & 15, lk = l >> 4;

    f32x4 acc[2][8];
#pragma unroll
    for (int m = 0; m < 2; ++m)
#pragma unroll
        for (int f = 0; f < 8; ++f) acc[m][f] = (f32x4){0.f, 0.f, 0.f, 0.f};

    const unsigned short* A = (const unsigned short*)Abf;
    const unsigned short* B = (const unsigned short*)Bbf;

    for (int kt = 0; kt < 4; ++kt) {
#pragma unroll
        for (int i = 0; i < 4; ++i) {
            int fi = i * 256 + tid;
            int row = fi >> 3, seg = fi & 7;
            int dseg = seg ^ (row & 7);
            *(short8*)&As[row * 64 + dseg * 8] =
                *(const short8*)&A[(r0 + row) * 256 + kt * 64 + seg * 8];
            *(short8*)&Bs[row * 64 + dseg * 8] =
                *(const short8*)&B[(c0 + row) * 256 + kt * 64 + seg * 8];
        }
        __syncthreads();
#pragma unroll
        for (int ks = 0; ks < 2; ++ks) {
            short8 a[2];
#pragma unroll
            for (int m = 0; m < 2; ++m) {
                int row = w * 32 + m * 16 + lr;
                a[m] = *(const short8*)&As[row * 64 + ((ks * 4 + lk) ^ (row & 7)) * 8];
            }
#pragma unroll
            for (int f = 0; f < 8; ++f) {
                int row = f * 16 + lr;
                short8 bfr = *(const short8*)&Bs[row * 64 + ((ks * 4 + lk) ^ (row & 7)) * 8];
#pragma unroll
                for (int m = 0; m < 2; ++m)
                    acc[m][f] = __builtin_amdgcn_mfma_f32_16x16x32_bf16(a[m], bfr, acc[m][f], 0, 0, 0);
            }
        }
        __syncthreads();
    }

    float sums[2][4] = {{0.f,0.f,0.f,0.f},{0.f,0.f,0.f,0.f}};
#pragma unroll
    for (int f = 0; f < 8; ++f) {
        float sbv = sb[c0 + f * 16 + lr];
#pragma unroll
        for (int m = 0; m < 2; ++m)
#pragma unroll
            for (int j = 0; j < 4; ++j) sums[m][j] += __expf(acc[m][f][j] + sbv);
    }
#pragma unroll
    for (int msk = 1; msk <= 8; msk <<= 1)
#pragma unroll
        for (int m = 0; m < 2; ++m)
#pragma unroll
            for (int j = 0; j < 4; ++j) sums[m][j] += __shfl_xor(sums[m][j], msk);
    if (lr == 0) {
#pragma unroll
        for (int m = 0; m < 2; ++m)
#pragma unroll
            for (int j = 0; j < 4; ++j)
                atomicAdd(&row_sum[r0 + w * 32 + m * 16 + lk * 4 + j], sums[m][j]);
    }
}

// ---------- per-row loss: log(sum_exp) - exact fp32 target logit, reduce to scalar
__global__ __launch_bounds__(256) void k_loss(const float* __restrict__ houtF,
    const float* __restrict__ sw, const float* __restrict__ sb,
    const int* __restrict__ tgts, const float* __restrict__ row_sum,
    float* __restrict__ out)
{
    int r = blockIdx.x * 256 + threadIdx.x;
    int tg = tgts[r];
    const float* h = houtF + (size_t)r * Hz;
    const float* wp = sw + tg;
    float acc = 0.f;
#pragma unroll 8
    for (int k = 0; k < Hz; ++k) acc += h[k] * wp[(size_t)k * Vv];
    float loss = logf(row_sum[r]) - (acc + sb[tg]);
#pragma unroll
    for (int m = 1; m < 64; m <<= 1) loss += __shfl_xor(loss, m);
    __shared__ float red[4];
    int l = threadIdx.x & 63, wv = threadIdx.x >> 6;
    if (l == 0) red[wv] = loss;
    __syncthreads();
    if (threadIdx.x == 0) {
        float s = red[0] + red[1] + red[2] + red[3];
        atomicAdd(out, s * (1.f / 8192.f));
    }
}

extern "C" void kernel_launch(void* const* d_in, const int* in_sizes, int n_in,
                              void* d_out, int out_size, void* d_ws, size_t ws_size,
                              hipStream_t stream)
{
    const int*   inp = (const int*)d_in[0];
    const int*   tgt = (const int*)d_in[1];
    const float* emb = (const float*)d_in[2];
    const float* W1  = (const float*)d_in[3];
    const float* b1  = (const float*)d_in[4];
    const float* W2  = (const float*)d_in[5];
    const float* b2  = (const float*)d_in[6];
    const float* sw  = (const float*)d_in[7];
    const float* sb  = (const float*)d_in[8];
    float* out = (float*)d_out;

    char* ws = (char*)d_ws;
    size_t off = 0;
    __hip_bfloat16* SWT  = (__hip_bfloat16*)(ws + off); off += (size_t)Vv * Hz * 2;       // 16,384,000
    __hip_bfloat16* XS   = (__hip_bfloat16*)(ws + off); off += (size_t)Tz * 32 * Hz * 2;  //  4,194,304
    float* HoutF         = (float*)(ws + off);          off += (size_t)8192 * Hz * 4;     //  8,388,608
    __hip_bfloat16* HoutB= (__hip_bfloat16*)(ws + off); off += (size_t)8192 * Hz * 2;     //  4,194,304
    float* row_sum       = (float*)(ws + off);          off += 8192 * 4;                  //     32,768
    __hip_bfloat16* h1b  = (__hip_bfloat16*)(ws + off); off += 2 * 32 * Hz * 2;           //     32,768
    __hip_bfloat16* h2b  = (__hip_bfloat16*)(ws + off); off += 2 * 32 * Hz * 2;           //     32,768
    unsigned* flags      = (unsigned*)(ws + off);       off += 64 * 16 * 4;               //      4,096
    // total ~33.3 MiB

    // zero row_sum + h1b + h2b + flags (contiguous) and out
    hipMemsetAsync(row_sum, 0, 8192 * 4 + 2 * 32768 + 64 * 16 * 4, stream);
    hipMemsetAsync(out, 0, sizeof(float), stream);

    k_swt<<<2000, 256, 0, stream>>>(sw, SWT);
    k_embed<<<8192, 64, 0, stream>>>(inp, emb, XS);
    k_lstm<<<64, 256, 0, stream>>>(XS, W1, b1, W2, b2, h1b, h2b, HoutF, HoutB, flags);
    k_gemm<<<dim3(64, 250), 256, 0, stream>>>(HoutB, SWT, sb, row_sum);
    k_loss<<<32, 256, 0, stream>>>(HoutF, sw, sb, tgt, row_sum, out);
}